// Round 5
// baseline (268.616 us; speedup 1.0000x reference)
//
#include <hip/hip_runtime.h>
#include <hip/hip_bf16.h>

typedef __attribute__((ext_vector_type(8))) short bf16x8;
typedef __attribute__((ext_vector_type(4))) short s16x4;
typedef __attribute__((ext_vector_type(4))) float f32x4;

#define NTOK 49

// LDS regions (shorts), total 31560 shorts = 63120 B -> 2 blocks/CU
#define RX   0        // [49][136]: X (ph0-1) -> O (ph3e-ph4)
#define RV   6664     // 4 heads x [32][72] V^T  (toks 49..63 zeroed once)
#define RQK  15880    // head h at RQK+h*3920: q[49][40], k[49][40]; pbuf[49][72] overlays q after B3
#define SM_TOT 31560

__device__ __forceinline__ short f2b(float v) {
    __hip_bfloat16 b = __float2bfloat16(v);
    return *reinterpret_cast<short*>(&b);
}

// region id: mask[w][i][j]==0 iff rid(i)==rid(j); slices [0,49)[49,53)[53,56)
__device__ __forceinline__ int rid_of(int t, int wh, int ww) {
    int i = t / 7;
    int j = t - 7 * i;
    int rh = (wh == 7) ? ((i < 4) ? 1 : 2) : 0;
    int rw = (ww == 7) ? ((j < 4) ? 1 : 2) : 0;
    return rh * 3 + rw;
}

__global__ void prep_kernel(const float* __restrict__ qkv_w,
                            const float* __restrict__ proj_w,
                            const float* __restrict__ rel_tab,
                            const int*   __restrict__ rel_idx,
                            short* __restrict__ wqkv_t,
                            short* __restrict__ wproj_t,
                            float* __restrict__ bmp) {
    int i = blockIdx.x * 256 + threadIdx.x;
    if (i < 384 * 128) {               // wqkv_t[n][k] = qkv_w[k][n]
        int n = i >> 7, k = i & 127;
        wqkv_t[i] = f2b(qkv_w[k * 384 + n]);
        return;
    }
    int j = i - 384 * 128;
    if (j < 128 * 128) {               // wproj_t[n][k] = proj_w[k][n]
        int n = j >> 7, k = j & 127;
        wproj_t[j] = f2b(proj_w[k * 128 + n]);
        return;
    }
    int l = j - 128 * 128;
    if (l < 4 * NTOK * 64) {           // bmp[h][q][k64] = tab[rel_idx[q][k]][h], pad 0
        int h = l / (NTOK * 64);
        int rem = l - h * (NTOK * 64);
        int q = rem >> 6, kk = rem & 63;
        bmp[l] = (kk < NTOK) ? rel_tab[rel_idx[q * NTOK + kk] * 4 + h] : 0.0f;
    }
}

__launch_bounds__(512, 4)
__global__ void swin_fused(const float* __restrict__ x,
                           const short* __restrict__ wqkv_t,
                           const float* __restrict__ qkv_b,
                           const short* __restrict__ wproj_t,
                           const float* __restrict__ proj_b,
                           const float* __restrict__ bmp,
                           float* __restrict__ out,
                           int niter) {
    __shared__ short sm[SM_TOT];

    const int tid = threadIdx.x;
    const int wv  = tid >> 6;
    const int ln  = tid & 63;
    const int g   = ln >> 4;
    const int c   = ln & 15;
    const int h    = wv >> 1;
    const int half = wv & 1;

    short* qbh = sm + RQK + h * 3920;    // [49][40]
    short* kbh = qbh + 1960;             // [49][40]
    short* pbh = qbh;                    // [49][72] overlay (post-B3)
    short* vbt = sm + RV + h * 2304;     // [32][72]

    // one-time: zero V^T pad toks 49..63 for all 128 dims
    for (int idx = tid; idx < 128 * 15; idx += 512) {
        int d = idx / 15, t = 49 + idx - (idx / 15) * 15;
        sm[RV + (d >> 5) * 2304 + (d & 31) * 72 + t] = 0;
    }

    const int w0 = blockIdx.x * niter;
    const f32x4* xall = (const f32x4*)x;

    // X prefetch registers (1568 f32x4 per window / 512 threads)
    f32x4 xr0, xr1, xr2, xr3;
    {
        const f32x4* p = xall + (size_t)w0 * 1568;
        xr0 = p[tid]; xr1 = p[tid + 512]; xr2 = p[tid + 1024];
        if (tid < 32) xr3 = p[tid + 1536];
    }

    for (int it = 0; it < niter; ++it) {
        const int b = w0 + it;
        if (it) __syncthreads();         // B5: prev window's LDS fully consumed

        // ---------- write X -> RX ----------
        {
            #define XWR(IDX, V) { int row = (IDX) >> 5; int col = ((IDX) & 31) * 4; \
                s16x4 pk; pk[0]=f2b((V)[0]); pk[1]=f2b((V)[1]); pk[2]=f2b((V)[2]); pk[3]=f2b((V)[3]); \
                *(s16x4*)&sm[RX + row * 136 + col] = pk; }
            XWR(tid, xr0) XWR(tid + 512, xr1) XWR(tid + 1024, xr2)
            if (tid < 32) XWR(tid + 1536, xr3)
            #undef XWR
        }
        __syncthreads();                 // B1

        const int cq = 32 * h + 16 * half;

        // ---------- phase 1a: Q,K channels [cq,cq+16) ----------
        {
            f32x4 accq[4], acck[4];
            #pragma unroll
            for (int nt = 0; nt < 4; ++nt) { accq[nt] = (f32x4){0.f,0.f,0.f,0.f}; acck[nt] = (f32x4){0.f,0.f,0.f,0.f}; }
            __builtin_amdgcn_s_setprio(1);
            #pragma unroll
            for (int kt = 0; kt < 4; ++kt) {
                bf16x8 awq = *(const bf16x8*)&wqkv_t[(cq + c) * 128 + 32*kt + 8*g];
                bf16x8 awk = *(const bf16x8*)&wqkv_t[(128 + cq + c) * 128 + 32*kt + 8*g];
                bf16x8 xv[4];
                #pragma unroll
                for (int nt = 0; nt < 4; ++nt) {
                    int tok = 16*nt + c; if (tok > 48) tok = 48;
                    xv[nt] = *(const bf16x8*)&sm[RX + tok * 136 + 32*kt + 8*g];
                }
                #pragma unroll
                for (int nt = 0; nt < 4; ++nt) {
                    accq[nt] = __builtin_amdgcn_mfma_f32_16x16x32_bf16(awq, xv[nt], accq[nt], 0, 0, 0);
                    acck[nt] = __builtin_amdgcn_mfma_f32_16x16x32_bf16(awk, xv[nt], acck[nt], 0, 0, 0);
                }
            }
            __builtin_amdgcn_s_setprio(0);
            const float qsc = 0.17677669529663687f;   // 32^-0.5 folded into q
            f32x4 bq4 = *(const f32x4*)&qkv_b[cq + 4*g];
            f32x4 bk4 = *(const f32x4*)&qkv_b[128 + cq + 4*g];
            #pragma unroll
            for (int nt = 0; nt < 4; ++nt) {
                int tok = 16*nt + c;
                if (tok >= NTOK) continue;
                s16x4 pq, pk2;
                #pragma unroll
                for (int r = 0; r < 4; ++r) {
                    pq[r]  = f2b((accq[nt][r] + bq4[r]) * qsc);
                    pk2[r] = f2b(acck[nt][r] + bk4[r]);
                }
                *(s16x4*)&qbh[tok * 40 + 16*half + 4*g] = pq;
                *(s16x4*)&kbh[tok * 40 + 16*half + 4*g] = pk2;
            }
        }

        // ---------- phase 1b: V channels -> vbt ----------
        {
            f32x4 accv[4];
            #pragma unroll
            for (int nt = 0; nt < 4; ++nt) accv[nt] = (f32x4){0.f,0.f,0.f,0.f};
            __builtin_amdgcn_s_setprio(1);
            #pragma unroll
            for (int kt = 0; kt < 4; ++kt) {
                bf16x8 awv = *(const bf16x8*)&wqkv_t[(256 + cq + c) * 128 + 32*kt + 8*g];
                bf16x8 xv[4];
                #pragma unroll
                for (int nt = 0; nt < 4; ++nt) {
                    int tok = 16*nt + c; if (tok > 48) tok = 48;
                    xv[nt] = *(const bf16x8*)&sm[RX + tok * 136 + 32*kt + 8*g];
                }
                #pragma unroll
                for (int nt = 0; nt < 4; ++nt)
                    accv[nt] = __builtin_amdgcn_mfma_f32_16x16x32_bf16(awv, xv[nt], accv[nt], 0, 0, 0);
            }
            __builtin_amdgcn_s_setprio(0);
            f32x4 bv4 = *(const f32x4*)&qkv_b[256 + cq + 4*g];
            const int d0 = 16*half + 4*g;
            #pragma unroll
            for (int nt = 0; nt < 4; ++nt) {
                int tok = 16*nt + c;
                if (tok >= NTOK) continue;
                vbt[(d0+0) * 72 + tok] = f2b(accv[nt][0] + bv4[0]);
                vbt[(d0+1) * 72 + tok] = f2b(accv[nt][1] + bv4[1]);
                vbt[(d0+2) * 72 + tok] = f2b(accv[nt][2] + bv4[2]);
                vbt[(d0+3) * 72 + tok] = f2b(accv[nt][3] + bv4[3]);
            }
        }
        __syncthreads();                 // B2: q,k,v^T ready; X dead

        // ---------- phase 2: S^T = K @ Q^T ----------
        const int ntq0 = 2 * half;
        f32x4 sA[4][2];
        {
            #pragma unroll
            for (int mt = 0; mt < 4; ++mt) { sA[mt][0] = (f32x4){0.f,0.f,0.f,0.f}; sA[mt][1] = (f32x4){0.f,0.f,0.f,0.f}; }
            bf16x8 ak[4];
            #pragma unroll
            for (int mt = 0; mt < 4; ++mt) {
                int kt2 = 16*mt + c; if (kt2 > 48) kt2 = 48;
                ak[mt] = *(const bf16x8*)&kbh[kt2 * 40 + 8*g];
            }
            __builtin_amdgcn_s_setprio(1);
            #pragma unroll
            for (int jj = 0; jj < 2; ++jj) {
                int qt = 16*(ntq0+jj) + c; if (qt > 48) qt = 48;
                bf16x8 bq = *(const bf16x8*)&qbh[qt * 40 + 8*g];
                #pragma unroll
                for (int mt = 0; mt < 4; ++mt)
                    sA[mt][jj] = __builtin_amdgcn_mfma_f32_16x16x32_bf16(ak[mt], bq, sA[mt][jj], 0, 0, 0);
            }
            __builtin_amdgcn_s_setprio(0);
        }
        __syncthreads();                 // B3: q,k fragments consumed; pbuf may overlay

        // prefetch next window's X (hidden under softmax+PV+proj)
        if (it + 1 < niter) {
            const f32x4* p = xall + (size_t)(b + 1) * 1568;
            xr0 = p[tid]; xr1 = p[tid + 512]; xr2 = p[tid + 1024];
            if (tid < 32) xr3 = p[tid + 1536];
        }

        // ---------- softmax + P -> pbuf + PV ----------
        {
            const int wh = (b >> 3) & 7, ww = b & 7;
            const bool wmask = (wh == 7) || (ww == 7);
            int ridk[16];
            if (wmask) {
                #pragma unroll
                for (int mt = 0; mt < 4; ++mt)
                    #pragma unroll
                    for (int r = 0; r < 4; ++r) {
                        int ktok = 16*mt + 4*g + r;
                        ridk[4*mt+r] = rid_of(ktok < NTOK ? ktok : 48, wh, ww);
                    }
            }
            #pragma unroll
            for (int jj = 0; jj < 2; ++jj) {
                int qtok = 16*(ntq0+jj) + c;
                int qtokc = qtok > 48 ? 48 : qtok;
                int ridq = wmask ? rid_of(qtokc, wh, ww) : 0;
                const float* bp = bmp + ((size_t)h * NTOK + qtokc) * 64;
                float e[16];
                float mx = -1e30f;
                #pragma unroll
                for (int mt = 0; mt < 4; ++mt) {
                    f32x4 b4 = *(const f32x4*)&bp[16*mt + 4*g];
                    #pragma unroll
                    for (int r = 0; r < 4; ++r) {
                        int ktok = 16*mt + 4*g + r;
                        float v = sA[mt][jj][r] + b4[r];
                        bool ok = (ktok < NTOK) && (!wmask || (ridk[4*mt+r] == ridq));
                        v = ok ? v : -1e30f;
                        e[4*mt+r] = v;
                        mx = fmaxf(mx, v);
                    }
                }
                mx = fmaxf(mx, __shfl_xor(mx, 16, 64));
                mx = fmaxf(mx, __shfl_xor(mx, 32, 64));
                float s = 0.f;
                #pragma unroll
                for (int ii = 0; ii < 16; ++ii) { float ev = __expf(e[ii] - mx); e[ii] = ev; s += ev; }
                s += __shfl_xor(s, 16, 64);
                s += __shfl_xor(s, 32, 64);
                float rs = 1.0f / s;
                if (qtok < NTOK) {
                    #pragma unroll
                    for (int mt = 0; mt < 4; ++mt) {
                        s16x4 pk;
                        pk[0] = f2b(e[4*mt+0] * rs);
                        pk[1] = f2b(e[4*mt+1] * rs);
                        pk[2] = f2b(e[4*mt+2] * rs);
                        pk[3] = f2b(e[4*mt+3] * rs);
                        *(s16x4*)&pbh[qtok * 72 + 16*mt + 4*g] = pk;
                    }
                }
            }

            // PV: O^T = V^T(32x64) @ P^T(64x64); P pad rows are 0
            f32x4 o[2][2];
            o[0][0]=(f32x4){0.f,0.f,0.f,0.f}; o[0][1]=(f32x4){0.f,0.f,0.f,0.f};
            o[1][0]=(f32x4){0.f,0.f,0.f,0.f}; o[1][1]=(f32x4){0.f,0.f,0.f,0.f};
            __builtin_amdgcn_s_setprio(1);
            #pragma unroll
            for (int kt = 0; kt < 2; ++kt) {
                bf16x8 av[2];
                #pragma unroll
                for (int mt = 0; mt < 2; ++mt)
                    av[mt] = *(const bf16x8*)&vbt[(16*mt + c) * 72 + 32*kt + 8*g];
                #pragma unroll
                for (int jj = 0; jj < 2; ++jj) {
                    int qt = 16*(ntq0+jj) + c; if (qt > 48) qt = 48;
                    bf16x8 bp2 = *(const bf16x8*)&pbh[qt * 72 + 32*kt + 8*g];
                    #pragma unroll
                    for (int mt = 0; mt < 2; ++mt)
                        o[mt][jj] = __builtin_amdgcn_mfma_f32_16x16x32_bf16(av[mt], bp2, o[mt][jj], 0, 0, 0);
                }
            }
            __builtin_amdgcn_s_setprio(0);
            // write O -> RX (X dead since B2)
            #pragma unroll
            for (int jj = 0; jj < 2; ++jj) {
                int qtok = 16*(ntq0+jj) + c;
                if (qtok >= NTOK) continue;
                #pragma unroll
                for (int mt = 0; mt < 2; ++mt) {
                    s16x4 pko;
                    pko[0] = f2b(o[mt][jj][0]); pko[1] = f2b(o[mt][jj][1]);
                    pko[2] = f2b(o[mt][jj][2]); pko[3] = f2b(o[mt][jj][3]);
                    *(s16x4*)&sm[RX + qtok * 136 + 32*h + 16*mt + 4*g] = pko;
                }
            }
        }
        __syncthreads();                 // B4: O complete

        // ---------- phase 4: Y^T = Wp^T @ O^T ----------
        {
            const int chb = 16 * wv;
            f32x4 po[4];
            #pragma unroll
            for (int j = 0; j < 4; ++j) po[j] = (f32x4){0.f,0.f,0.f,0.f};
            __builtin_amdgcn_s_setprio(1);
            #pragma unroll
            for (int kt = 0; kt < 4; ++kt) {
                bf16x8 aw = *(const bf16x8*)&wproj_t[(chb + c) * 128 + 32*kt + 8*g];
                #pragma unroll
                for (int j = 0; j < 4; ++j) {
                    int qt = 16*j + c; if (qt > 48) qt = 48;
                    bf16x8 bo = *(const bf16x8*)&sm[RX + qt * 136 + 32*kt + 8*g];
                    po[j] = __builtin_amdgcn_mfma_f32_16x16x32_bf16(aw, bo, po[j], 0, 0, 0);
                }
            }
            __builtin_amdgcn_s_setprio(0);
            f32x4 pb4 = *(const f32x4*)&proj_b[chb + 4*g];
            float* op = out + (size_t)b * 6272;
            #pragma unroll
            for (int j = 0; j < 4; ++j) {
                int qtok = 16*j + c;
                if (qtok >= NTOK) continue;
                f32x4 wq;
                wq[0] = po[j][0] + pb4[0]; wq[1] = po[j][1] + pb4[1];
                wq[2] = po[j][2] + pb4[2]; wq[3] = po[j][3] + pb4[3];
                *(f32x4*)&op[qtok * 128 + chb + 4*g] = wq;
            }
        }
    }
}

extern "C" void kernel_launch(void* const* d_in, const int* in_sizes, int n_in,
                              void* d_out, int out_size, void* d_ws, size_t ws_size,
                              hipStream_t stream) {
    const float* x       = (const float*)d_in[0];
    const float* qkv_w   = (const float*)d_in[1];
    const float* qkv_b   = (const float*)d_in[2];
    const float* proj_w  = (const float*)d_in[3];
    const float* proj_b  = (const float*)d_in[4];
    const float* rel_tab = (const float*)d_in[5];
    const int*   rel_idx = (const int*)d_in[7];

    char* ws = (char*)d_ws;
    short* wqkv_t  = (short*)ws;                        // 98304 B
    short* wproj_t = (short*)(ws + 98304);              // 32768 B
    float* bmp     = (float*)(ws + 98304 + 32768);      // 50176 B

    int total = 384*128 + 128*128 + 4*NTOK*64;
    prep_kernel<<<(total + 255) / 256, 256, 0, stream>>>(qkv_w, proj_w, rel_tab, rel_idx,
                                                         wqkv_t, wproj_t, bmp);

    int B_ = in_sizes[0] / (NTOK * 128);                // 4096
    int blocks, niter;
    if (B_ % 512 == 0) { blocks = 512; niter = B_ / 512; }
    else               { blocks = B_;  niter = 1; }
    swin_fused<<<blocks, 512, 0, stream>>>(x, wqkv_t, qkv_b, wproj_t, proj_b, bmp,
                                           (float*)d_out, niter);
}